// Round 8
// baseline (115.574 us; speedup 1.0000x reference)
//
#include <hip/hip_runtime.h>
#include <hip/hip_bf16.h>

// Problem constants (B=2, S=2048, E=1024, H=16, Dh=64)
#define S_LEN 2048
#define EMB   1024
#define NH    16
#define DH    64
#define QKV_LD 3072   // 3*EMB

typedef __attribute__((ext_vector_type(8)))  __bf16 bf16x8;
typedef __attribute__((ext_vector_type(4)))  __bf16 bf16x4;
typedef __attribute__((ext_vector_type(4)))  float  f32x4;
typedef __attribute__((ext_vector_type(16))) float  f32x16;
typedef __attribute__((ext_vector_type(2)))  unsigned int u32x2;

// ---- async global->LDS (16B per lane; LDS dst = wave-uniform base) ----
__device__ __forceinline__ void gl_lds16(const void* g, void* l) {
  __builtin_amdgcn_global_load_lds(
      (const __attribute__((address_space(1))) void*)g,
      (__attribute__((address_space(3))) void*)l,
      16, 0, 0);
}

// ---------------- fused prep: cast x -> bf16, transpose+cast both weights --
__global__ __launch_bounds__(256)
void prep_fused(const float* __restrict__ x, __bf16* __restrict__ xb,
                const float* __restrict__ w_attn, __bf16* __restrict__ wat,
                const float* __restrict__ w_proj, __bf16* __restrict__ wpt,
                int n8) {
  __shared__ float T[64][65];
  const int bid = blockIdx.x;
  const int tid = threadIdx.x;

  if (bid < 2048) {
    int i = bid * 256 + tid;
    if (i >= n8) return;
    const f32x4* p = (const f32x4*)(x + (size_t)i * 8);
    f32x4 a = p[0], b = p[1];
    bf16x8 o;
    #pragma unroll
    for (int j = 0; j < 4; j++) { o[j] = (__bf16)a[j]; o[4 + j] = (__bf16)b[j]; }
    *(bf16x8*)(xb + (size_t)i * 8) = o;
    return;
  }

  const float* W; __bf16* Wt; int K, N, k0, n0;
  if (bid < 2048 + 768) {
    int t = bid - 2048;                 // w_attn: N=3072 -> 48 x-tiles, 16 k-tiles
    W = w_attn; Wt = wat; K = 1024; N = 3072;
    n0 = (t % 48) * 64; k0 = (t / 48) * 64;
  } else {
    int t = bid - 2816;                 // w_proj: 16 x 16 tiles
    W = w_proj; Wt = wpt; K = 1024; N = 1024;
    n0 = (t & 15) * 64; k0 = (t >> 4) * 64;
  }
  #pragma unroll
  for (int t = 0; t < 16; t++) {
    int idx = tid + t * 256;
    int r = idx >> 6, c = idx & 63;
    T[r][c] = W[(size_t)(k0 + r) * N + n0 + c];
  }
  __syncthreads();
  #pragma unroll
  for (int t = 0; t < 16; t++) {
    int idx = tid + t * 256;
    int r = idx >> 6, c = idx & 63;     // r = local n, c = local k
    Wt[(size_t)(n0 + r) * K + k0 + c] = (__bf16)T[c][r];
  }
}

// ---------------- bf16 MFMA GEMM: C(MxN) = A(MxK) @ Bt(NxK)^T -------------
#define TM 128
#define TK 32

template <typename OutT, int TNv>
__global__ __launch_bounds__(256, 2)
void gemm_bf16_mfma(const __bf16* __restrict__ A, const __bf16* __restrict__ Bt,
                    OutT* __restrict__ C, int M, int N, int K) {
  __shared__ __align__(16) __bf16 As[2][TM][TK];
  __shared__ __align__(16) __bf16 Bs[2][TNv][TK];
  const int tid  = threadIdx.x;
  const int lane = tid & 63;
  const int w    = tid >> 6;
  const int wr   = w >> 1, wc = w & 1;
  const int brow = blockIdx.y * TM;
  const int bcol = blockIdx.x * TNv;
  const int l15  = lane & 15;
  const int grp  = lane >> 4;

  constexpr int NBI = TNv / 64;        // B staging issues per wave
  constexpr int WCT = TNv / 2;         // wave column tile
  constexpr int NN  = WCT / 16;        // n-fragments per wave

  auto stage = [&](int k0, int buf) {
    #pragma unroll
    for (int j = 0; j < 2; j++) {       // A: 128x32 = 512 chunks, 2/wave
      const int cid = w * 128 + j * 64 + lane;
      const int row = cid >> 2, k8 = (cid & 3) * 8;
      gl_lds16(A + (size_t)(brow + row) * K + k0 + k8,
               &As[buf][0][0] + (size_t)(w * 128 + j * 64) * 8);
    }
    #pragma unroll
    for (int j = 0; j < NBI; j++) {     // B: TNv x 32 chunks
      const int cid = (w * NBI + j) * 64 + lane;
      const int row = cid >> 2, k8 = (cid & 3) * 8;
      gl_lds16(Bt + (size_t)(bcol + row) * K + k0 + k8,
               &Bs[buf][0][0] + (size_t)((w * NBI + j) * 64) * 8);
    }
  };

  f32x4 acc[4][NN];
  #pragma unroll
  for (int m = 0; m < 4; m++)
    #pragma unroll
    for (int n = 0; n < NN; n++) acc[m][n] = (f32x4){0.f, 0.f, 0.f, 0.f};

  stage(0, 0);
  __syncthreads();                      // drains prologue vmcnt

  const int nk = K / TK;
  for (int kt = 0; kt < nk; kt++) {
    const int cur = kt & 1;
    if (kt + 1 < nk) stage((kt + 1) * TK, cur ^ 1);   // prefetch under MFMA

    bf16x8 a[4], b[NN];
    #pragma unroll
    for (int m = 0; m < 4; m++)
      a[m] = *(const bf16x8*)&As[cur][wr * 64 + m * 16 + l15][grp * 8];
    #pragma unroll
    for (int n = 0; n < NN; n++)
      b[n] = *(const bf16x8*)&Bs[cur][wc * WCT + n * 16 + l15][grp * 8];
    #pragma unroll
    for (int m = 0; m < 4; m++)
      #pragma unroll
      for (int n = 0; n < NN; n++)
        acc[m][n] = __builtin_amdgcn_mfma_f32_16x16x32_bf16(a[m], b[n], acc[m][n], 0, 0, 0);

    __syncthreads();   // all waves done reading cur; prefetch landed
  }

  #pragma unroll
  for (int m = 0; m < 4; m++)
    #pragma unroll
    for (int r = 0; r < 4; r++) {
      const size_t row = (size_t)(brow + wr * 64 + m * 16 + grp * 4 + r);
      #pragma unroll
      for (int n = 0; n < NN; n++)
        C[row * N + bcol + wc * WCT + n * 16 + l15] = (OutT)acc[m][n][r];
    }
}

// ---------------- MFMA flash attention v21: QB=128, 8 waves ---------------
// R0-R7 synthesis: time ~ (block-iterations per CU) x (per-key-tile cost);
// KB fattening scaled cost with work (v20), occupancy moves did nothing.
// The per-key costs (K/V staging, X-wait, 3 barriers) amortize over Q-rows
// served: QB=128 halves block-iterations (16896 -> 8704), staging traffic,
// and barrier events, while each WAVE runs the byte-identical v17 engine
// (32q x 64k).  8 waves/block = 4 q-subtiles x 2 key-halves; 512 blocks
// zigzag-paired (t,15-t -> 34+34 iters per CU pair).  Masking: last TWO
// key-tiles masked (upper-half rows hit their diagonal one tile early;
// their final tile is fully-masked and contributes exactly zero).
// Epilogue kh-merge runs twice (qh-pairs 0/1 then 2/3) to reuse 16 KB LDS.
#define QB 128
#define KB 64
#define QSCALE 0.18033688f   // 0.125 * log2(e)

__global__ __launch_bounds__(512, 4)
void attn_mfma(const __bf16* __restrict__ qkv, __bf16* __restrict__ y) {
  // 17408 B: Ks [64][64] bf16 (8KB) | Vs 4096 bf16 (8KB) | exML 1KB
  __shared__ __align__(16) char SMEM[17408];
  __bf16 (*Ks)[64] = (__bf16 (*)[64])SMEM;
  __bf16* Vs = (__bf16*)(SMEM + 8192);

  const int tid  = threadIdx.x;
  const int lane = tid & 63;
  const int w    = tid >> 6;          // 0..7

  // XCD swizzle + zigzag pairing: per-XCD sequence alternates long/short so
  // the 2 co-resident blocks/CU sum to a constant 34 iterations.
  const int bid = blockIdx.x;                 // 0..511
  const int swz = (bid & 7) * 64 + (bid >> 3);
  const int g   = swz >> 4;                   // (b,h) group 0..31
  const int i   = swz & 15;
  const int zig = (i & 1) ? (i >> 1) : 15 - (i >> 1);
  const int qtile = (g & 1) ? 15 - zig : zig; // 0..15 (128-row tiles)
  const int h = g & 15, b = g >> 4;

  const __bf16* base = qkv + (size_t)b * S_LEN * QKV_LD;

  const int l31 = lane & 31;
  const int hl  = lane >> 5;          // lane half (0/1)
  const int qh  = w >> 1;             // q-subtile 0..3 (32 rows each)
  const int kh  = w & 1;              // k-half of the 64-key tile

  // tr_read per-lane base (v10 law; kh selects 32-key half)
  const int voff32 = ((lane >> 4) & 1) * 2048 + hl * 128 + (lane & 15) * 8
                   + kh * 1024;

  // 512 lanes stage exactly one 16B chunk each (512 chunks = 8KB per tile)
  auto stageK = [&](int j0) {
    const int cid = w * 64 + lane;               // chunk 0..511
    const int r = cid >> 3, pc = cid & 7;
    const int lc = pc ^ (r & 7);                 // inverse swizzle on source
    gl_lds16(base + (size_t)(j0 + r) * QKV_LD + EMB + h * DH + lc * 8,
             SMEM + cid * 16);
  };
  auto stageV = [&](int j0) {
    const int cid = w * 64 + lane;
    const int db = cid >> 7, sk = (cid >> 3) & 15;
    const int jr = (cid >> 1) & 3, ch = cid & 1;
    gl_lds16(base + (size_t)(j0 + sk * 4 + jr) * QKV_LD + 2 * EMB + h * DH
                  + db * 16 + ch * 8,
             SMEM + 8192 + cid * 16);
  };

  const int q = qtile * QB + qh * 32 + l31;      // this lane's q row

  // Q B-fragments (col=q, k_hw=d): qf[dq][i] = Q[q][dq*16 + hl*8 + i]
  bf16x8 qf[4];
  {
    const __bf16* qp = base + (size_t)q * QKV_LD + h * DH;
    #pragma unroll
    for (int dq = 0; dq < 4; dq++) {
      bf16x8 v = *(const bf16x8*)(qp + dq * 16 + hl * 8);
      #pragma unroll
      for (int i2 = 0; i2 < 8; i2++) qf[dq][i2] = (__bf16)((float)v[i2] * QSCALE);
    }
  }

  f32x16 o_acc[2];
  #pragma unroll
  for (int d2 = 0; d2 < 2; d2++)
    #pragma unroll
    for (int r = 0; r < 16; r++) o_acc[d2][r] = 0.f;
  float m = -1e30f, l = 0.f;

  // One K-tile (v17 engine, byte-identical per wave): X-barrier, QK^T,
  // tr-issue, Z-barrier+stageK, Y-barrier+stageV, softmax, PV.
  auto iter = [&](int j0, bool masked, int jn, bool do_stage) {
    asm volatile("s_waitcnt vmcnt(0)" ::: "memory");
    __builtin_amdgcn_s_barrier();                      // X: K,V of tile landed
    __builtin_amdgcn_sched_barrier(0);

    // ---- S^T = K Q (32k x 32q, chained over d) ----
    f32x16 s;
    #pragma unroll
    for (int r = 0; r < 16; r++) s[r] = 0.f;
    const int krow = kh * 32 + l31;
    __builtin_amdgcn_s_setprio(1);
    #pragma unroll
    for (int dq = 0; dq < 4; dq++) {
      bf16x8 kf = *(const bf16x8*)&Ks[krow][((dq * 2 + hl) ^ (krow & 7)) * 8];
      s = __builtin_amdgcn_mfma_f32_32x32x16_bf16(kf, qf[dq], s, 0, 0, 0);
    }
    __builtin_amdgcn_s_setprio(0);

    if (masked) {
      const int lim = q - j0 - kh * 32 - 4 * hl;   // keep if (reg&3)+8*(reg>>2) <= lim
      #pragma unroll
      for (int r = 0; r < 16; r++) {
        const int kl = (r & 3) + 8 * (r >> 2);
        if (kl > lim) s[r] = -2e30f;    // -2e30: exp2(s-m)==0 even when m=-1e30
      }
    }

    // ---- issue all 8 V^T transpose reads (latency covered by max tree) ----
    const unsigned vb =
        (unsigned)(uintptr_t)(__attribute__((address_space(3))) char*)(Vs)
        + (unsigned)voff32;
    u32x2 tv[8];
    asm volatile("ds_read_b64_tr_b16 %0, %1 offset:0"    : "=v"(tv[0]) : "v"(vb));
    asm volatile("ds_read_b64_tr_b16 %0, %1 offset:256"  : "=v"(tv[1]) : "v"(vb));
    asm volatile("ds_read_b64_tr_b16 %0, %1 offset:512"  : "=v"(tv[2]) : "v"(vb));
    asm volatile("ds_read_b64_tr_b16 %0, %1 offset:768"  : "=v"(tv[3]) : "v"(vb));
    asm volatile("ds_read_b64_tr_b16 %0, %1 offset:4096" : "=v"(tv[4]) : "v"(vb));
    asm volatile("ds_read_b64_tr_b16 %0, %1 offset:4352" : "=v"(tv[5]) : "v"(vb));
    asm volatile("ds_read_b64_tr_b16 %0, %1 offset:4608" : "=v"(tv[6]) : "v"(vb));
    asm volatile("ds_read_b64_tr_b16 %0, %1 offset:4864" : "=v"(tv[7]) : "v"(vb));

    // ---- max reduce: depth-4 tree + ONE cross-half shuffle ----
    float x0 = fmaxf(s[0], s[8]),  x1 = fmaxf(s[1], s[9]);
    float x2 = fmaxf(s[2], s[10]), x3 = fmaxf(s[3], s[11]);
    float x4 = fmaxf(s[4], s[12]), x5 = fmaxf(s[5], s[13]);
    float x6 = fmaxf(s[6], s[14]), x7 = fmaxf(s[7], s[15]);
    x0 = fmaxf(x0, x4); x1 = fmaxf(x1, x5);
    x2 = fmaxf(x2, x6); x3 = fmaxf(x3, x7);
    x0 = fmaxf(x0, x2); x1 = fmaxf(x1, x3);
    float tmax = fmaxf(x0, x1);
    tmax = fmaxf(tmax, __shfl_xor(tmax, 32));

    const bool grow = !__all(tmax <= m + 8.0f);
    float corr = 1.f;
    if (grow) {
      const float mnew = fmaxf(m, tmax);
      corr = __builtin_amdgcn_exp2f(m - mnew);
      m = mnew;
    }

    __builtin_amdgcn_s_barrier();                      // Z: all QK reads done
    if (do_stage) stageK(jn);                          // Ks dead -> overwrite

    asm volatile("s_waitcnt lgkmcnt(0)" ::: "memory"); // tr data in regs
    __builtin_amdgcn_sched_barrier(0);
    __builtin_amdgcn_s_barrier();                      // Y: all tr reads done
    if (do_stage) stageV(jn);                          // Vs dead -> overwrite

    // ---- exp2 + tree psum ----
    float ps0 = 0.f, ps1 = 0.f, ps2 = 0.f, ps3 = 0.f;
    #pragma unroll
    for (int r = 0; r < 16; r += 4) {
      float p0 = __builtin_amdgcn_exp2f(s[r]     - m);
      float p1 = __builtin_amdgcn_exp2f(s[r + 1] - m);
      float p2 = __builtin_amdgcn_exp2f(s[r + 2] - m);
      float p3 = __builtin_amdgcn_exp2f(s[r + 3] - m);
      s[r] = p0; s[r + 1] = p1; s[r + 2] = p2; s[r + 3] = p3;
      ps0 += p0; ps1 += p1; ps2 += p2; ps3 += p3;
    }
    float psum = (ps0 + ps1) + (ps2 + ps3);

    // ---- P^T B-frags: fully in-lane ----
    bf16x8 pb0, pb1;
    #pragma unroll
    for (int i2 = 0; i2 < 8; i2++) {
      pb0[i2] = (__bf16)s[i2];
      pb1[i2] = (__bf16)s[8 + i2];
    }

    // ---- O-rescale must precede PV ----
    if (grow) {
      #pragma unroll
      for (int d2 = 0; d2 < 2; d2++)
        #pragma unroll
        for (int r = 0; r < 16; r++) o_acc[d2][r] *= corr;
    }

    // ---- 4 back-to-back PV MFMAs (tv already drained) ----
    __builtin_amdgcn_s_setprio(1);
    #pragma unroll
    for (int d2 = 0; d2 < 2; d2++) {
      bf16x8 a0, a1;
      ((u32x2*)&a0)[0] = tv[d2 * 4 + 0]; ((u32x2*)&a0)[1] = tv[d2 * 4 + 1];
      ((u32x2*)&a1)[0] = tv[d2 * 4 + 2]; ((u32x2*)&a1)[1] = tv[d2 * 4 + 3];
      o_acc[d2] = __builtin_amdgcn_mfma_f32_32x32x16_bf16(a0, pb0, o_acc[d2], 0, 0, 0);
      o_acc[d2] = __builtin_amdgcn_mfma_f32_32x32x16_bf16(a1, pb1, o_acc[d2], 0, 0, 0);
    }
    __builtin_amdgcn_s_setprio(0);

    // ---- l-update (off the PV critical path) ----
    psum += __shfl_xor(psum, 32);
    l = grow ? (l * corr + psum) : (l + psum);
  };

  // prologue: stage tile 0 (X-barrier of iteration 0 drains it)
  stageK(0);
  stageV(0);

  // nt = 2*qtile + 2 key-tiles; last TWO are masked (qh 0/1 rows hit their
  // diagonal at tile nt-2; tile nt-1 is fully masked for them -> zero).
  const int nt = 2 * qtile + 2;
  #pragma unroll 1
  for (int tt = 0; tt < nt; tt++) {
    iter(tt * KB, tt >= nt - 2, (tt + 1) * KB, tt + 1 < nt);
  }

  // ---- kh-pair merge through LDS (two rounds: qh 0/1 then qh 2/3) ----
  __syncthreads();     // all waves done; reuse SMEM as exchange space
  float* exO  = (float*)SMEM;               // [32 rows][128 slots] = 16 KB
  float* exML = (float*)(SMEM + 16384);     // [2][128] f32 = 1 KB
  const int slot = (qh & 1) * 64 + lane;
  #pragma unroll 1
  for (int ep = 0; ep < 2; ep++) {
    const bool mine = (qh >> 1) == ep;
    if (mine && kh) {
      #pragma unroll
      for (int r = 0; r < 16; r++) {
        exO[r * 128 + slot]        = o_acc[0][r];
        exO[(16 + r) * 128 + slot] = o_acc[1][r];
      }
      exML[slot]       = m;
      exML[128 + slot] = l;
    }
    __syncthreads();
    if (mine && !kh) {
      const float m1  = exML[slot];
      const float l1v = exML[128 + slot];
      const float mm = fmaxf(m, m1);
      const float c0 = __builtin_amdgcn_exp2f(m - mm);
      const float c1 = __builtin_amdgcn_exp2f(m1 - mm);
      const float inv = 1.f / (l * c0 + l1v * c1);
      __bf16* yrow = y + ((size_t)(b * S_LEN + q)) * EMB + h * DH;
      #pragma unroll
      for (int d2 = 0; d2 < 2; d2++)
        #pragma unroll
        for (int rq = 0; rq < 4; rq++) {
          bf16x4 o4;
          #pragma unroll
          for (int jj = 0; jj < 4; jj++) {
            const int r = rq * 4 + jj;
            float v = (o_acc[d2][r] * c0 + exO[(d2 * 16 + r) * 128 + slot] * c1) * inv;
            o4[jj] = (__bf16)v;
          }
          // d = d2*32 + rq*8 + hl*4 + jj
          *(bf16x4*)&yrow[d2 * 32 + rq * 8 + hl * 4] = o4;
        }
    }
    __syncthreads();
  }
}

// ---------------- Launch ----------------
extern "C" void kernel_launch(void* const* d_in, const int* in_sizes, int n_in,
                              void* d_out, int out_size, void* d_ws, size_t ws_size,
                              hipStream_t stream) {
  const float* x      = (const float*)d_in[0];  // (B, S, E)
  const float* w_attn = (const float*)d_in[1];  // (E, 3E)
  const float* w_proj = (const float*)d_in[2];  // (E, E)
  float* out = (float*)d_out;                   // (B, S, E)

  const int B = in_sizes[0] / (S_LEN * EMB);    // = 2
  const int M = B * S_LEN;                      // 4096

  // bf16 workspace layout
  __bf16* xb   = (__bf16*)d_ws;                       // M x E          (8 MB)
  __bf16* wat  = xb  + (size_t)M * EMB;               // 3E x E transp  (6 MB)
  __bf16* wpt  = wat + (size_t)QKV_LD * EMB;          // E x E transp   (2 MB)
  __bf16* qkvb = wpt + (size_t)EMB * EMB;             // M x 3E         (24 MB)
  __bf16* yb   = qkvb + (size_t)M * QKV_LD;           // M x E          (8 MB)

  // 0) fused prep: cast + both weight transposes in one launch
  {
    int n8 = (M * EMB) / 8;   // 524288 -> 2048 cast blocks
    prep_fused<<<dim3(3072), 256, 0, stream>>>(x, xb, w_attn, wat, w_proj, wpt, n8);
  }

  // 1) qkv = x @ w_attn  (bf16 out, TN=128: grid 768 = 3 blocks/CU)
  dim3 g1(QKV_LD / 128, M / TM);
  gemm_bf16_mfma<__bf16, 128><<<g1, 256, 0, stream>>>(xb, wat, qkvb, M, QKV_LD, EMB);

  // 2) y = causal_attention(qkv)  [v21: QB=128, 8 waves, 512 blocks]
  attn_mfma<<<dim3(512), 512, 0, stream>>>(qkvb, yb);

  // 3) out = y @ w_proj  (f32 out, TN=64: grid 512 = 2 blocks/CU)
  dim3 g3(EMB / 64, M / TM);
  gemm_bf16_mfma<float, 64><<<g3, 256, 0, stream>>>(yb, wpt, out, M, EMB, EMB);
}